// Round 8
// baseline (603.569 us; speedup 1.0000x reference)
//
#include <hip/hip_runtime.h>
#include <math.h>

// GCN 2-layer: conv1(x) -> BN -> ReLU -> conv2
//   h = x @ W (MFMA f16 GEMM, f32 accumulate)
//   agg[i] = dinv[i]^2*h[i] + sum_{e: dst=i} dinv[src]*dinv[i]*h[src] + b
// Intermediates f16 in CHANNEL-BLOCKED layout h_blk[slice][n][16]: aggregation
// is split into 16-channel slices, slice s pinned to XCD s via blockIdx%8 ->
// per-XCD gather table (3.2 MB) is L2-resident; gathers become L2 hits.
// Edge prep: dst>>6 binning (bulk reservation) + per-bucket CSR.

typedef _Float16 f16;
typedef _Float16 f16x2 __attribute__((ext_vector_type(2)));
typedef _Float16 f16x8 __attribute__((ext_vector_type(8)));
typedef float f32x4 __attribute__((ext_vector_type(4)));

static constexpr int KDIM = 128;
static constexpr int MAXNB = 1600;  // buckets (n<=102400)
static constexpr int CAP = 2560;    // edges/bucket cap (mean 2048, ~11 sigma)
static constexpr int CHUNK = 8192;  // binA edges per block
static constexpr int BINT = 512;    // binA threads (8 waves)
static constexpr int WTP = 136;     // LDS W^T row pitch (f16): 128 + 8 pad

// ---------------- edge binning (per-block bulk reservation) ----------------
__global__ __launch_bounds__(BINT) void binA_kernel(
    const int* __restrict__ src, const int* __restrict__ dst, int E,
    int* __restrict__ bcur, unsigned int* __restrict__ bins, int nbuck) {
  __shared__ int hist[MAXNB];
  __shared__ int base[MAXNB];
  const int tid = threadIdx.x;
  for (int b = tid; b < nbuck; b += BINT) hist[b] = 0;
  __syncthreads();
  const int e0 = blockIdx.x * CHUNK;
  const int e1 = min(e0 + CHUNK, E);
  for (int e = e0 + tid; e < e1; e += BINT) atomicAdd(&hist[dst[e] >> 6], 1);
  __syncthreads();
  for (int b = tid; b < nbuck; b += BINT) {
    int c = hist[b];
    base[b] = c ? atomicAdd(&bcur[b], c) : 0;
    hist[b] = 0;  // reuse as local cursor
  }
  __syncthreads();
  for (int e = e0 + tid; e < e1; e += BINT) {
    int d = dst[e];
    int b = d >> 6;
    int lp = atomicAdd(&hist[b], 1);
    int p = base[b] + lp;
    if (p < CAP)
      bins[(size_t)b * CAP + p] = (unsigned int)src[e] | ((unsigned int)(d & 63) << 17);
  }
}

// ---------------- bucket-count exclusive scan (1 block; nbuck <= 2048) ----------------
__global__ __launch_bounds__(1024) void bscan_kernel(
    const int* __restrict__ bcur, int nbuck, int* __restrict__ bbase,
    int* __restrict__ off_n) {
  __shared__ int sh[1024];
  const int t = threadIdx.x;
  int a = (2 * t < nbuck) ? min(bcur[2 * t], CAP) : 0;
  int b = (2 * t + 1 < nbuck) ? min(bcur[2 * t + 1], CAP) : 0;
  sh[t] = a + b;
  __syncthreads();
  for (int o = 1; o < 1024; o <<= 1) {
    int v = (t >= o) ? sh[t - o] : 0;
    __syncthreads();
    sh[t] += v;
    __syncthreads();
  }
  int excl = (t > 0) ? sh[t - 1] : 0;
  if (2 * t < nbuck) bbase[2 * t] = excl;
  if (2 * t + 1 < nbuck) bbase[2 * t + 1] = excl + a;
  if (t == 1023) off_n[0] = sh[1023];
}

// ---------------- per-bucket CSR build + degrees ----------------
__global__ __launch_bounds__(256) void csrfill_kernel(
    const unsigned int* __restrict__ bins, const int* __restrict__ bcur,
    const int* __restrict__ bbase, int* __restrict__ csr, int* __restrict__ off,
    float* __restrict__ dinv, int n) {
  __shared__ int hist[64];
  __shared__ int pref[64];
  __shared__ int lcur[64];
  const int tid = threadIdx.x;
  const int b = blockIdx.x;
  const int cnt = min(bcur[b], CAP);
  const unsigned int* bp = bins + (size_t)b * CAP;
  if (tid < 64) hist[tid] = 0;
  __syncthreads();
  for (int e = tid; e < cnt; e += 256) atomicAdd(&hist[bp[e] >> 17], 1);
  __syncthreads();
  if (tid < 64) pref[tid] = hist[tid];
  __syncthreads();
  for (int o = 1; o < 64; o <<= 1) {
    int v = (tid < 64 && tid >= o) ? pref[tid - o] : 0;
    __syncthreads();
    if (tid < 64) pref[tid] += v;
    __syncthreads();
  }
  if (tid < 64) {
    int node = b * 64 + tid;
    if (node < n) {
      int excl = bbase[b] + pref[tid] - hist[tid];
      off[node] = excl;
      lcur[tid] = excl;
      dinv[node] = rsqrtf((float)(hist[tid] + 1));  // +1 self-loop
    }
  }
  __syncthreads();
  for (int e = tid; e < cnt; e += 256) {
    unsigned int pk = bp[e];
    int r = pk >> 17;
    int p = atomicAdd(&lcur[r], 1);
    csr[p] = (int)(pk & 0x1FFFF);
  }
}

// ---------------- GEMM1 (MFMA): h1_blk[8][n][16] = x[M x 128](f32) @ W1 ----------------
__global__ __launch_bounds__(256) void gemm1_kernel(
    const float* __restrict__ A, const float* __restrict__ W, f16* __restrict__ Cb,
    int M) {
  __shared__ f16 Wt[128][WTP];
  const int tid = threadIdx.x;
  for (int idx = tid; idx < 128 * 128; idx += 256) {
    int k = idx >> 7, nn = idx & 127;  // W[k][nn]
    Wt[nn][k] = (f16)W[idx];
  }
  __syncthreads();
  const int wave = tid >> 6;
  const int lane = tid & 63;
  const int r = lane & 15;
  const int kg = lane >> 4;
  const int row0 = blockIdx.x * 64 + wave * 16;
  const bool valid = (row0 + r) < M;
  const float* arow = A + (size_t)(row0 + r) * KDIM;
  f32x4 acc[8];
#pragma unroll
  for (int nf = 0; nf < 8; ++nf) acc[nf] = (f32x4){0.f, 0.f, 0.f, 0.f};
#pragma unroll
  for (int ks = 0; ks < 4; ++ks) {
    const int k0 = ks * 32 + kg * 8;
    f16x8 a;
#pragma unroll
    for (int z = 0; z < 8; ++z) a[z] = (f16)0.f;
    if (valid) {
      float4 u = *reinterpret_cast<const float4*>(arow + k0);
      float4 v = *reinterpret_cast<const float4*>(arow + k0 + 4);
      a[0] = (f16)u.x; a[1] = (f16)u.y; a[2] = (f16)u.z; a[3] = (f16)u.w;
      a[4] = (f16)v.x; a[5] = (f16)v.y; a[6] = (f16)v.z; a[7] = (f16)v.w;
    }
#pragma unroll
    for (int nf = 0; nf < 8; ++nf) {
      f16x8 b = *reinterpret_cast<const f16x8*>(&Wt[nf * 16 + r][k0]);
      acc[nf] = __builtin_amdgcn_mfma_f32_16x16x32_f16(a, b, acc[nf], 0, 0, 0);
    }
  }
  const int crow = row0 + (lane >> 4) * 4;
  const int ccol = lane & 15;
#pragma unroll
  for (int q = 0; q < 4; ++q) {
    int rr = crow + q;
    if (rr < M) {
#pragma unroll
      for (int nf = 0; nf < 8; ++nf)
        Cb[((size_t)nf * M + rr) * 16 + ccol] = (f16)acc[nf][q];
    }
  }
}

// ---------------- GEMM2 (MFMA): h2_blk[4][n][16] = relu(bn(agg1)) @ W2, rows *= dinv ----------------
// A read from blocked agg1: channel c -> Ab[(c>>4)*M*16 + row*16 + (c&15)]
__global__ __launch_bounds__(256) void gemm2_kernel(
    const f16* __restrict__ Ab, const float* __restrict__ W, f16* __restrict__ Cb,
    int M, const float* __restrict__ ss, const float* __restrict__ dinv) {
  __shared__ f16 Wt[64][WTP];
  const int tid = threadIdx.x;
  for (int idx = tid; idx < 128 * 64; idx += 256) {
    int k = idx >> 6, nn = idx & 63;  // W[k][nn]
    Wt[nn][k] = (f16)W[idx];
  }
  __syncthreads();
  const int wave = tid >> 6;
  const int lane = tid & 63;
  const int r = lane & 15;
  const int kg = lane >> 4;
  const int row0 = blockIdx.x * 64 + wave * 16;
  const bool valid = (row0 + r) < M;
  f32x4 acc[4];
#pragma unroll
  for (int nf = 0; nf < 4; ++nf) acc[nf] = (f32x4){0.f, 0.f, 0.f, 0.f};
#pragma unroll
  for (int ks = 0; ks < 4; ++ks) {
    const int k0 = ks * 32 + kg * 8;
    f16x8 a;
#pragma unroll
    for (int z = 0; z < 8; ++z) a[z] = (f16)0.f;
    if (valid) {
      const int slice = k0 >> 4;
      const int koff = k0 & 15;
      f16x8 raw = *reinterpret_cast<const f16x8*>(
          &Ab[((size_t)slice * M + row0 + r) * 16 + koff]);
      float4 s0 = *reinterpret_cast<const float4*>(&ss[k0]);
      float4 s1 = *reinterpret_cast<const float4*>(&ss[k0 + 4]);
      float4 t0 = *reinterpret_cast<const float4*>(&ss[128 + k0]);
      float4 t1 = *reinterpret_cast<const float4*>(&ss[128 + k0 + 4]);
      a[0] = (f16)fmaxf((float)raw[0] * s0.x + t0.x, 0.f);
      a[1] = (f16)fmaxf((float)raw[1] * s0.y + t0.y, 0.f);
      a[2] = (f16)fmaxf((float)raw[2] * s0.z + t0.z, 0.f);
      a[3] = (f16)fmaxf((float)raw[3] * s0.w + t0.w, 0.f);
      a[4] = (f16)fmaxf((float)raw[4] * s1.x + t1.x, 0.f);
      a[5] = (f16)fmaxf((float)raw[5] * s1.y + t1.y, 0.f);
      a[6] = (f16)fmaxf((float)raw[6] * s1.z + t1.z, 0.f);
      a[7] = (f16)fmaxf((float)raw[7] * s1.w + t1.w, 0.f);
    }
#pragma unroll
    for (int nf = 0; nf < 4; ++nf) {
      f16x8 b = *reinterpret_cast<const f16x8*>(&Wt[nf * 16 + r][k0]);
      acc[nf] = __builtin_amdgcn_mfma_f32_16x16x32_f16(a, b, acc[nf], 0, 0, 0);
    }
  }
  const int crow = row0 + (lane >> 4) * 4;
  const int ccol = lane & 15;
#pragma unroll
  for (int q = 0; q < 4; ++q) {
    int rr = crow + q;
    if (rr < M) {
      float dv = dinv[rr];
#pragma unroll
      for (int nf = 0; nf < 4; ++nf)
        Cb[((size_t)nf * M + rr) * 16 + ccol] = (f16)(acc[nf][q] * dv);
    }
  }
}

// ---------------- conv1 sliced aggregation: block -> (node group, slice) ----------------
// slice s = blockIdx%8 -> XCD s (dispatch round-robin); slice table 3.2MB L2-resident.
// wave = 1 node; lane: eo=lane>>3 (8 edges), cp=lane&7 (8 f16x2 = 16 ch).
__global__ __launch_bounds__(256) void agg1s_kernel(
    const f16* __restrict__ hblk, const float* __restrict__ dinv,
    const int* __restrict__ off, const int* __restrict__ csr,
    const float* __restrict__ bias, f16* __restrict__ oblk, int n) {
  const int s = blockIdx.x & 7;
  const int g = blockIdx.x >> 3;
  const int w = threadIdx.x >> 6;
  const int lane = threadIdx.x & 63;
  const int i = g * 4 + w;
  if (i >= n) return;
  const int eo = lane >> 3;
  const int cp = lane & 7;
  const float di = dinv[i];
  const f16* hs = hblk + (size_t)s * n * 16;
  float e0 = 0.f, e1 = 0.f;
  const int beg = off[i], end = off[i + 1];
  for (int j = beg; j < end; j += 16) {
    int j0 = j + eo, j1 = j0 + 8;
    bool p0 = j0 < end, p1 = j1 < end;
    int s0 = p0 ? csr[j0] : i;
    int s1 = p1 ? csr[j1] : i;
    float w0 = p0 ? dinv[s0] : 0.f;
    float w1 = p1 ? dinv[s1] : 0.f;
    f16x2 v0 = *reinterpret_cast<const f16x2*>(&hs[(size_t)s0 * 16 + 2 * cp]);
    f16x2 v1 = *reinterpret_cast<const f16x2*>(&hs[(size_t)s1 * 16 + 2 * cp]);
    e0 += w0 * (float)v0[0] + w1 * (float)v1[0];
    e1 += w0 * (float)v0[1] + w1 * (float)v1[1];
  }
  e0 += __shfl_xor(e0, 8, 64);  e1 += __shfl_xor(e1, 8, 64);
  e0 += __shfl_xor(e0, 16, 64); e1 += __shfl_xor(e1, 16, 64);
  e0 += __shfl_xor(e0, 32, 64); e1 += __shfl_xor(e1, 32, 64);
  if (eo == 0) {
    float2 bi = *reinterpret_cast<const float2*>(&bias[s * 16 + 2 * cp]);
    f16x2 hv = *reinterpret_cast<const f16x2*>(&hs[(size_t)i * 16 + 2 * cp]);
    f16x2 o;
    o[0] = (f16)(di * (e0 + di * (float)hv[0]) + bi.x);
    o[1] = (f16)(di * (e1 + di * (float)hv[1]) + bi.y);
    *reinterpret_cast<f16x2*>(&oblk[((size_t)s * n + i) * 16 + 2 * cp]) = o;
  }
}

// ---------------- conv2 sliced aggregation: 4 slices x 2 node-halves ----------------
// h2 rows pre-scaled by dinv; out f32 row-major [n][64].
__global__ __launch_bounds__(256) void agg2s_kernel(
    const f16* __restrict__ hblk, const float* __restrict__ dinv,
    const int* __restrict__ off, const int* __restrict__ csr,
    const float* __restrict__ bias, float* __restrict__ out, int n) {
  const int q = blockIdx.x & 7;
  const int s = q >> 1;
  const int half = q & 1;
  const int g = blockIdx.x >> 3;
  const int w = threadIdx.x >> 6;
  const int lane = threadIdx.x & 63;
  const int i = g * 8 + w * 2 + half;
  if (i >= n) return;
  const int eo = lane >> 3;
  const int cp = lane & 7;
  const float di = dinv[i];
  const f16* hs = hblk + (size_t)s * n * 16;
  float e0 = 0.f, e1 = 0.f;
  const int beg = off[i], end = off[i + 1];
  for (int j = beg; j < end; j += 16) {
    int j0 = j + eo, j1 = j0 + 8;
    bool p0 = j0 < end, p1 = j1 < end;
    int s0 = p0 ? csr[j0] : i;
    int s1 = p1 ? csr[j1] : i;
    float w0 = p0 ? 1.f : 0.f;
    float w1 = p1 ? 1.f : 0.f;
    f16x2 v0 = *reinterpret_cast<const f16x2*>(&hs[(size_t)s0 * 16 + 2 * cp]);
    f16x2 v1 = *reinterpret_cast<const f16x2*>(&hs[(size_t)s1 * 16 + 2 * cp]);
    e0 += w0 * (float)v0[0] + w1 * (float)v1[0];
    e1 += w0 * (float)v0[1] + w1 * (float)v1[1];
  }
  e0 += __shfl_xor(e0, 8, 64);  e1 += __shfl_xor(e1, 8, 64);
  e0 += __shfl_xor(e0, 16, 64); e1 += __shfl_xor(e1, 16, 64);
  e0 += __shfl_xor(e0, 32, 64); e1 += __shfl_xor(e1, 32, 64);
  if (eo == 0) {
    f16x2 hv = *reinterpret_cast<const f16x2*>(&hs[(size_t)i * 16 + 2 * cp]);
    float2 bi = *reinterpret_cast<const float2*>(&bias[s * 16 + 2 * cp]);
    float2 o;
    o.x = di * (e0 + (float)hv[0]) + bi.x;
    o.y = di * (e1 + (float)hv[1]) + bi.y;
    *reinterpret_cast<float2*>(&out[(size_t)i * 64 + s * 16 + 2 * cp]) = o;
  }
}

// ---------------- BN stats (blocked f16 input, f32 accumulate) ----------------
__global__ void bnstat_kernel(const f16* __restrict__ ab, int n, float* __restrict__ acc) {
  const int c = threadIdx.x & 127;
  const int half = threadIdx.x >> 7;
  const int rstart = blockIdx.x * 2 + half;
  const int rstep = gridDim.x * 2;
  const f16* base = ab + (size_t)(c >> 4) * n * 16 + (c & 15);
  float s = 0.f, ss = 0.f;
  for (int r = rstart; r < n; r += rstep) {
    float v = (float)base[(size_t)r * 16];
    s += v;
    ss += v * v;
  }
  atomicAdd(&acc[c], s);
  atomicAdd(&acc[128 + c], ss);
}

__global__ void bnfin_kernel(const float* __restrict__ acc, const float* __restrict__ gamma,
                             const float* __restrict__ beta, int n, float* __restrict__ ss) {
  const int c = threadIdx.x;
  const float inv_n = 1.f / (float)n;
  const float mean = acc[c] * inv_n;
  const float var = acc[128 + c] * inv_n - mean * mean;
  const float sc = gamma[c] * rsqrtf(var + 1e-5f);
  ss[c] = sc;
  ss[128 + c] = beta[c] - mean * sc;
}

// ---------------- launch ----------------
extern "C" void kernel_launch(void* const* d_in, const int* in_sizes, int n_in,
                              void* d_out, int out_size, void* d_ws, size_t ws_size,
                              hipStream_t stream) {
  const float* x = (const float*)d_in[0];
  const int* ei = (const int*)d_in[1];
  const float* W1 = (const float*)d_in[2];
  const float* b1 = (const float*)d_in[3];
  const float* gamma = (const float*)d_in[4];
  const float* beta = (const float*)d_in[5];
  const float* W2 = (const float*)d_in[6];
  const float* b2 = (const float*)d_in[7];
  float* out = (float*)d_out;

  const int n = in_sizes[0] / 128;
  const int E = in_sizes[1] / 2;
  const int* src = ei;
  const int* dst = ei + E;
  const int nbuck = (n + 63) / 64;

  char* p = (char*)d_ws;
  auto carve = [&](size_t bytes) {
    char* r = p;
    p += (bytes + 255) & ~(size_t)255;
    return r;
  };
  int* bcur = (int*)carve((size_t)nbuck * 4);
  float* bnacc = (float*)carve(256 * 4);
  const size_t zero_bytes = (size_t)((char*)(bnacc + 256) - (char*)bcur);
  int* bbase = (int*)carve((size_t)(nbuck + 1) * 4);
  float* bnss = (float*)carve(256 * 4);
  int* off = (int*)carve((size_t)(n + 1) * 4);
  float* dinv = (float*)carve((size_t)n * 4);
  unsigned int* bins = (unsigned int*)carve((size_t)nbuck * CAP * 4);  // 16 MB
  int* csr = (int*)carve((size_t)E * 4);                               // 12.8 MB
  f16* h1b = (f16*)carve((size_t)n * 128 * 2);                         // [8][n][16], 25.6 MB
  f16* agg1b = (f16*)carve((size_t)n * 128 * 2);                       // [8][n][16], 25.6 MB
  f16* h2b = h1b;  // reuse: h1 dead after agg1s ([4][n][16], 12.8 MB)

  hipMemsetAsync(bcur, 0, zero_bytes, stream);

  const int ngb = (n + 63) / 64;

  gemm1_kernel<<<ngb, 256, 0, stream>>>(x, W1, h1b, n);

  binA_kernel<<<(E + CHUNK - 1) / CHUNK, BINT, 0, stream>>>(src, dst, E, bcur, bins, nbuck);
  bscan_kernel<<<1, 1024, 0, stream>>>(bcur, nbuck, bbase, off + n);
  csrfill_kernel<<<nbuck, 256, 0, stream>>>(bins, bcur, bbase, csr, off, dinv, n);

  agg1s_kernel<<<((n + 3) / 4) * 8, 256, 0, stream>>>(h1b, dinv, off, csr, b1, agg1b, n);

  bnstat_kernel<<<512, 256, 0, stream>>>(agg1b, n, bnacc);
  bnfin_kernel<<<1, 128, 0, stream>>>(bnacc, gamma, beta, n, bnss);

  gemm2_kernel<<<ngb, 256, 0, stream>>>(agg1b, W2, h2b, n, bnss, dinv);
  agg2s_kernel<<<((n + 7) / 8) * 8, 256, 0, stream>>>(h2b, dinv, off, csr, b2, out, n);
}